// Round 7
// baseline (251.057 us; speedup 1.0000x reference)
//
#include <hip/hip_runtime.h>

#define BB 32
#define AA 8
#define NN 20000
#define DD 128
#define PP 50
#define DELTA 1e-3f

typedef unsigned long long ull;

// ---------------- conv1: [32,4,84,84] * [32,4,8,8] s4 -> [32,32,20,20] relu ----------------
__global__ __launch_bounds__(256) void conv1_k(const float* __restrict__ x,
                                               const float* __restrict__ w,
                                               const float* __restrict__ bias,
                                               float* __restrict__ y) {
    int idx = blockIdx.x * 256 + threadIdx.x;
    if (idx >= 32 * 32 * 20 * 20) return;
    int ox = idx % 20;
    int t = idx / 20;
    int oy = t % 20; t /= 20;
    int oc = t % 32;
    int b = t / 32;
    float acc = bias[oc];
    const float* xb = x + (size_t)b * 4 * 84 * 84;
    const float* wk = w + oc * 4 * 64;
    for (int ic = 0; ic < 4; ic++) {
        const float* xc = xb + ic * 84 * 84 + (oy * 4) * 84 + ox * 4;  // 16B-aligned
        const float* wc = wk + ic * 64;
#pragma unroll
        for (int ky = 0; ky < 8; ky++) {
            const float4* xr = (const float4*)(xc + ky * 84);
            const float4* wr = (const float4*)(wc + ky * 8);
            float4 x0 = xr[0], x1 = xr[1];
            float4 w0 = wr[0], w1 = wr[1];
            acc += x0.x * w0.x + x0.y * w0.y + x0.z * w0.z + x0.w * w0.w
                 + x1.x * w1.x + x1.y * w1.y + x1.z * w1.z + x1.w * w1.w;
        }
    }
    y[idx] = fmaxf(acc, 0.f);
}

// ---------------- conv2: [32,32,20,20] * [64,32,4,4] s2 -> [32,64,9,9] relu ----------------
__global__ __launch_bounds__(256) void conv2_k(const float* __restrict__ x,
                                               const float* __restrict__ w,
                                               const float* __restrict__ bias,
                                               float* __restrict__ y) {
    int idx = blockIdx.x * 256 + threadIdx.x;
    if (idx >= 32 * 64 * 9 * 9) return;
    int ox = idx % 9;
    int t = idx / 9;
    int oy = t % 9; t /= 9;
    int oc = t % 64;
    int b = t / 64;
    float acc = bias[oc];
    const float* xb = x + (size_t)b * 32 * 400;
    const float* wk = w + oc * 32 * 16;
    for (int ic = 0; ic < 32; ic++) {
        const float* xc = xb + ic * 400 + (oy * 2) * 20 + ox * 2;  // 8B-aligned
        const float* wc = wk + ic * 16;                            // 16B-aligned
#pragma unroll
        for (int ky = 0; ky < 4; ky++) {
            const float2* xr = (const float2*)(xc + ky * 20);
            float2 x0 = xr[0], x1 = xr[1];
            float4 wv = ((const float4*)(wc + ky * 4))[0];
            acc += x0.x * wv.x + x0.y * wv.y + x1.x * wv.z + x1.y * wv.w;
        }
    }
    y[idx] = fmaxf(acc, 0.f);
}

// ---------------- conv3: [32,64,9,9] * [64,64,3,3] s1 -> [32,64,7,7] relu ----------------
__global__ __launch_bounds__(256) void conv3_k(const float* __restrict__ x,
                                               const float* __restrict__ w,
                                               const float* __restrict__ bias,
                                               float* __restrict__ y) {
    int idx = blockIdx.x * 256 + threadIdx.x;
    if (idx >= 32 * 64 * 7 * 7) return;
    int ox = idx % 7;
    int t = idx / 7;
    int oy = t % 7; t /= 7;
    int oc = t % 64;
    int b = t / 64;
    float acc = bias[oc];
    const float* xb = x + (size_t)b * 64 * 81;
    const float* wk = w + oc * 64 * 9;
    for (int ic = 0; ic < 64; ic++) {
        const float* xc = xb + ic * 81 + oy * 9 + ox;
        const float* wc = wk + ic * 9;
#pragma unroll
        for (int ky = 0; ky < 3; ky++)
#pragma unroll
            for (int kx = 0; kx < 3; kx++)
                acc += xc[ky * 9 + kx] * wc[ky * 3 + kx];
    }
    y[idx] = fmaxf(acc, 0.f);
}

// ---------------- fc: [32,3136] @ [128,3136]^T + b -> h [32,128] ----------------
__global__ __launch_bounds__(256) void fc_k(const float* __restrict__ x,
                                            const float* __restrict__ w,
                                            const float* __restrict__ bias,
                                            float* __restrict__ h) {
    __shared__ float sx[3136];
    int b = blockIdx.x >> 3;
    int g = blockIdx.x & 7;
    int tid = threadIdx.x;
    const float4* xr = (const float4*)(x + (size_t)b * 3136);
    float4* sx4w = (float4*)sx;
    for (int i = tid; i < 784; i += 256) sx4w[i] = xr[i];
    __syncthreads();
    int oc_local = tid >> 4;
    int kslice = tid & 15;
    int oc = g * 16 + oc_local;
    const float4* wr = (const float4*)(w + (size_t)oc * 3136);
    const float4* sx4 = (const float4*)sx;
    float acc = 0.f;
#pragma unroll 7
    for (int j = 0; j < 49; j++) {
        int i = kslice + 16 * j;
        float4 a = sx4[i], c = wr[i];
        acc += a.x * c.x + a.y * c.y + a.z * c.z + a.w * c.w;
    }
#pragma unroll
    for (int m = 8; m >= 1; m >>= 1) acc += __shfl_xor(acc, m);
    if (kslice == 0) h[b * 128 + oc] = acc + bias[oc];
}

// ---------------- dist4: lane-per-row distances from a swizzled LDS key tile ----------------
// grid (313, AA), block 256 (4 waves). Block stages 64 key rows once (coalesced float4,
// rotation-swizzled so lane-per-row b128 reads spread across banks); each lane accumulates a
// full 128-elem squared distance for its row (NO cross-lane reduce); waves cover the action's
// m samples round-robin. Routing (per-action sample list) computed inline by wave 0.
__global__ __launch_bounds__(256) void dist4_k(const float* __restrict__ h,
                                               const int* __restrict__ actions,
                                               const float* __restrict__ keys,
                                               float* __restrict__ d2) {
    int a = blockIdx.y;
    int tid = threadIdx.x;
    int lane = tid & 63, wave = tid >> 6;
    __shared__ float4 tile[64 * 32];   // 32 KB, slot-rotated per row
    __shared__ float4 hl4[BB * 32];    // up to 16 KB used
    __shared__ int sl[BB];
    __shared__ int s_m;

    // inline routing: wave 0 builds this action's sample list
    if (wave == 0) {
        int act = (lane < BB) ? actions[lane] : -1;
        ull mask = __ballot(act == a);
        if (act == a) {
            int pos = __popcll(mask & ((1ull << lane) - 1));
            sl[pos] = lane;
        }
        if (lane == 0) s_m = __popcll(mask);
    }
    __syncthreads();
    int m = s_m;
    if (m == 0) return;

    // stage h vectors for the m samples
    for (int i = tid; i < m * 32; i += 256) {
        int s = i >> 5, g = i & 31;
        hl4[i] = ((const float4*)(h + sl[s] * DD))[g];
    }

    // stage 64-row key tile, coalesced; write slot rotated by (row & 31)
    int r0 = blockIdx.x * 64;
    int valid = min(64, NN - r0);
    const float4* kb4 = (const float4*)(keys + (size_t)a * NN * DD);
#pragma unroll
    for (int i = 0; i < 8; i++) {
        int idx = i * 256 + tid;
        int row = idx >> 5, g = idx & 31;
        if (row < valid)
            tile[row * 32 + ((g + (row & 31)) & 31)] = kb4[(size_t)(r0 + row) * 32 + g];
    }
    __syncthreads();

    int row = lane;
    if (row < valid) {
        int c = row & 31;
        const float4* trow = &tile[row * 32];
        for (int s = wave; s < m; s += 4) {
            const float4* hp = &hl4[s * 32];
            float acc = 0.f;
#pragma unroll 8
            for (int g = 0; g < 32; g++) {
                float4 kv = trow[(g + c) & 31];
                float4 hv = hp[g];
                float dx = hv.x - kv.x, dy = hv.y - kv.y;
                float dz = hv.z - kv.z, dw = hv.w - kv.w;
                acc += dx * dx + dy * dy + dz * dz + dw * dw;
            }
            d2[(size_t)sl[s] * NN + r0 + row] = acc;  // lane-coalesced
        }
    }
}

// ---------------- select: fused exact top-50 (two-level radix on float bits) + weighted sum ----
// d2 >= 0 so float bits are order-isomorphic. key = (bits << 32) | idx reproduces lax.top_k's
// stable (lowest-index-on-tie) order exactly. grid BB, block 1024.
__global__ __launch_bounds__(1024) void select_k(const float* __restrict__ d2,
                                                 const float* __restrict__ values,
                                                 const int* __restrict__ actions,
                                                 float* __restrict__ q) {
    const int NB = 8160;   // coarse buckets: bits >> 18 (covers all finite floats)
    const int CAP = 512;
    int b = blockIdx.x, tid = threadIdx.x;
    int lane = tid & 63, wave = tid >> 6;  // 16 waves
    __shared__ int hist[NB];
    __shared__ int fhist[1024];
    __shared__ float cd[CAP];
    __shared__ int ci[CAP];
    __shared__ int scounter;
    __shared__ int s_t, s_below;
    __shared__ int s_ft;
    __shared__ int wsum[16];
    __shared__ float rw[16], rwv[16];

    const float* db = d2 + (size_t)b * NN;
    for (int i = tid; i < NB; i += 1024) hist[i] = 0;
    fhist[tid] = 0;
    if (tid == 0) scounter = 0;
    __syncthreads();

    // ---- pass 1: coarse histogram ----
    for (int i = tid; i < NN; i += 1024)
        atomicAdd(&hist[__float_as_uint(db[i]) >> 18], 1);
    __syncthreads();

    // ---- find coarse cutoff bucket t: smallest t with cum(t) >= PP ----
    {
        int s = 0;
#pragma unroll
        for (int u = 0; u < 8; u++) s += hist[tid * 8 + u];  // strip [8*tid, 8*tid+8)
        int sc = s;
#pragma unroll
        for (int m = 1; m < 64; m <<= 1) {
            int o = __shfl_up(sc, m);
            if (lane >= m) sc += o;
        }
        if (lane == 63) wsum[wave] = sc;
        __syncthreads();
        if (tid < 16) {
            int vc = wsum[tid];
            for (int m = 1; m < 16; m <<= 1) {
                int o = __shfl_up(vc, m);
                if (tid >= m) vc += o;
            }
            wsum[tid] = vc;
        }
        __syncthreads();
        int incl = ((wave == 0) ? 0 : wsum[wave - 1]) + sc;
        int excl = incl - s;
        if (excl < PP && incl >= PP) {  // exactly one strip crosses
            int c = excl;
#pragma unroll
            for (int u = 0; u < 8; u++) {
                int bkt = tid * 8 + u;
                int hv = hist[bkt];
                if (c < PP && c + hv >= PP) { s_t = bkt; s_below = c; }
                c += hv;
            }
        }
    }
    __syncthreads();
    int t = s_t, below = s_below;

    // ---- pass 2: fine histogram (next 10 bits) within bucket t ----
    for (int i = tid; i < NN; i += 1024) {
        unsigned bits = __float_as_uint(db[i]);
        if ((int)(bits >> 18) == t) atomicAdd(&fhist[(bits >> 8) & 1023], 1);
    }
    __syncthreads();

    // ---- find fine cutoff ft: smallest with below + finecum(ft) >= PP ----
    {
        int s = fhist[tid];
        int sc = s;
#pragma unroll
        for (int m = 1; m < 64; m <<= 1) {
            int o = __shfl_up(sc, m);
            if (lane >= m) sc += o;
        }
        if (lane == 63) wsum[wave] = sc;
        __syncthreads();
        if (tid < 16) {
            int vc = wsum[tid];
            for (int m = 1; m < 16; m <<= 1) {
                int o = __shfl_up(vc, m);
                if (tid >= m) vc += o;
            }
            wsum[tid] = vc;
        }
        __syncthreads();
        int incl = ((wave == 0) ? 0 : wsum[wave - 1]) + sc;
        int excl = incl - s;
        if (below + excl < PP && below + incl >= PP) s_ft = tid;
    }
    __syncthreads();
    int ft = s_ft;

    // ---- pass 3: collect superset of top-PP ----
    for (int i = tid; i < NN; i += 1024) {
        unsigned bits = __float_as_uint(db[i]);
        int c = (int)(bits >> 18);
        bool take = (c < t) || (c == t && (int)((bits >> 8) & 1023) <= ft);
        if (take) {
            int slot = atomicAdd(&scounter, 1);
            if (slot < CAP) { cd[slot] = db[i]; ci[slot] = i; }
        }
    }
    __syncthreads();
    int k = min(scounter, CAP);

    // ---- exact stable rank-count on k (~60) elements + weighted sum ----
    float w = 0.f, wv = 0.f;
    int a = actions[b];
    for (int s = tid; s < k; s += 1024) {
        ull key = ((ull)__float_as_uint(cd[s]) << 32) | (unsigned)ci[s];
        int cnt = 0;
        for (int j = 0; j < k; j++) {
            ull kj = ((ull)__float_as_uint(cd[j]) << 32) | (unsigned)ci[j];
            cnt += (kj < key);
        }
        if (cnt < PP) {
            float dd = fmaxf(cd[s], 0.f);
            float ww = 1.f / (dd + DELTA);
            w += ww;
            wv += ww * values[(size_t)a * NN + ci[s]];
        }
    }
#pragma unroll
    for (int m = 32; m >= 1; m >>= 1) {
        w += __shfl_xor(w, m);
        wv += __shfl_xor(wv, m);
    }
    if (lane == 0) { rw[wave] = w; rwv[wave] = wv; }
    __syncthreads();
    if (tid < 16) {
        float tw = rw[tid], twv = rwv[tid];
#pragma unroll
        for (int m = 8; m >= 1; m >>= 1) {
            tw += __shfl_xor(tw, m);
            twv += __shfl_xor(twv, m);
        }
        if (tid == 0) q[b] = twv / tw;
    }
}

extern "C" void kernel_launch(void* const* d_in, const int* in_sizes, int n_in,
                              void* d_out, int out_size, void* d_ws, size_t ws_size,
                              hipStream_t stream) {
    const float* states = (const float*)d_in[0];
    const int* actions = (const int*)d_in[1];
    const float* c1w = (const float*)d_in[2];
    const float* c1b = (const float*)d_in[3];
    const float* c2w = (const float*)d_in[4];
    const float* c2b = (const float*)d_in[5];
    const float* c3w = (const float*)d_in[6];
    const float* c3b = (const float*)d_in[7];
    const float* fcw = (const float*)d_in[8];
    const float* fcb = (const float*)d_in[9];
    const float* keys = (const float*)d_in[10];
    const float* vals = (const float*)d_in[11];
    float* out = (float*)d_out;

    float* ws = (float*)d_ws;
    float* c1o = ws;                    // 409600
    float* c2o = c1o + 409600;          // 165888
    float* c3o = c2o + 165888;          // 100352
    float* h   = c3o + 100352;          // 4096
    float* d2  = h + 4096;              // 640000

    conv1_k<<<(409600 + 255) / 256, 256, 0, stream>>>(states, c1w, c1b, c1o);
    conv2_k<<<(165888 + 255) / 256, 256, 0, stream>>>(c1o, c2w, c2b, c2o);
    conv3_k<<<(100352 + 255) / 256, 256, 0, stream>>>(c2o, c3w, c3b, c3o);
    fc_k<<<256, 256, 0, stream>>>(c3o, fcw, fcb, h);
    dist4_k<<<dim3(313, AA), 256, 0, stream>>>(h, actions, keys, d2);
    select_k<<<BB, 1024, 0, stream>>>(d2, vals, actions, out);
}

// Round 8
// 248.520 us; speedup vs baseline: 1.0102x; 1.0102x over previous
//
#include <hip/hip_runtime.h>

#define BB 32
#define AA 8
#define NN 20000
#define DD 128
#define PP 50
#define DELTA 1e-3f

typedef unsigned long long ull;

// ---------------- conv1: [32,4,84,84] * [32,4,8,8] s4 -> [32,32,20,20] relu ----------------
// grid 128 = (b, og of 8 oc). w-tile in LDS; each thread computes 8 oc per position,
// x window (8 floats per (ic,ky)) held in registers and reused across the 8 oc.
__global__ __launch_bounds__(256) void conv1_k(const float* __restrict__ x,
                                               const float* __restrict__ w,
                                               const float* __restrict__ bias,
                                               float* __restrict__ y) {
    int b = blockIdx.x >> 2;
    int og = blockIdx.x & 3;
    int tid = threadIdx.x;
    __shared__ __align__(16) float wl[8 * 256];  // [oc8][ic4][ky8][kx8]
    {
        const float4* wg = (const float4*)(w + og * 2048);
        float4* wl4 = (float4*)wl;
        for (int i = tid; i < 512; i += 256) wl4[i] = wg[i];
    }
    float bb[8];
#pragma unroll
    for (int o = 0; o < 8; o++) bb[o] = bias[og * 8 + o];
    __syncthreads();

    const float* xb = x + (size_t)b * 4 * 84 * 84;
    for (int pp = tid; pp < 400; pp += 256) {
        int oy = pp / 20, ox = pp % 20;
        float acc[8];
#pragma unroll
        for (int o = 0; o < 8; o++) acc[o] = bb[o];
        for (int ic = 0; ic < 4; ic++) {
            const float* xc = xb + ic * 7056 + (oy * 4) * 84 + ox * 4;  // 16B-aligned
#pragma unroll
            for (int ky = 0; ky < 8; ky++) {
                const float4* xr = (const float4*)(xc + ky * 84);
                float4 x0 = xr[0], x1 = xr[1];
                float xv[8] = {x0.x, x0.y, x0.z, x0.w, x1.x, x1.y, x1.z, x1.w};
                const float* wrow = wl + ic * 64 + ky * 8;
#pragma unroll
                for (int o = 0; o < 8; o++) {
                    const float* wo = wrow + o * 256;
#pragma unroll
                    for (int kx = 0; kx < 8; kx++) acc[o] += xv[kx] * wo[kx];
                }
            }
        }
#pragma unroll
        for (int o = 0; o < 8; o++)
            y[((size_t)(b * 32 + og * 8 + o)) * 400 + pp] = fmaxf(acc[o], 0.f);
    }
}

// ---------------- conv2: [32,32,20,20] * [64,32,4,4] s2 -> [32,64,9,9] relu ----------------
// grid 256 = (b, og of 8 oc). Full per-sample x (51.2KB) + w-tile (16.4KB) in LDS.
// Threads tid<162: pos = tid/2, half = tid&1 -> 4 oc each.
__global__ __launch_bounds__(256) void conv2_k(const float* __restrict__ x,
                                               const float* __restrict__ w,
                                               const float* __restrict__ bias,
                                               float* __restrict__ y) {
    int b = blockIdx.x >> 3;
    int og = blockIdx.x & 7;
    int tid = threadIdx.x;
    __shared__ __align__(16) float xs[12800];   // [32ic][400]
    __shared__ __align__(16) float ws[8 * 512]; // [oc8][ic32][ky4][kx4]
    {
        const float4* xg = (const float4*)(x + (size_t)b * 12800);
        float4* xs4 = (float4*)xs;
        for (int i = tid; i < 3200; i += 256) xs4[i] = xg[i];
        const float4* wg = (const float4*)(w + og * 4096);
        float4* ws4 = (float4*)ws;
        for (int i = tid; i < 1024; i += 256) ws4[i] = wg[i];
    }
    __syncthreads();

    if (tid < 162) {
        int pos = tid >> 1, half = tid & 1;
        int oy = pos / 9, ox = pos % 9;
        float acc[4];
#pragma unroll
        for (int o = 0; o < 4; o++) acc[o] = bias[og * 8 + half * 4 + o];
        for (int ic = 0; ic < 32; ic++) {
            const float* xrow = xs + ic * 400 + (oy * 2) * 20 + ox * 2;
#pragma unroll
            for (int ky = 0; ky < 4; ky++) {
                float x0 = xrow[ky * 20], x1 = xrow[ky * 20 + 1];
                float x2 = xrow[ky * 20 + 2], x3 = xrow[ky * 20 + 3];
                const float* wrow = ws + (half * 4) * 512 + ic * 16 + ky * 4;
#pragma unroll
                for (int o = 0; o < 4; o++) {
                    const float* wo = wrow + o * 512;
                    acc[o] += x0 * wo[0] + x1 * wo[1] + x2 * wo[2] + x3 * wo[3];
                }
            }
        }
#pragma unroll
        for (int o = 0; o < 4; o++)
            y[((size_t)(b * 64 + og * 8 + half * 4 + o)) * 81 + pos] = fmaxf(acc[o], 0.f);
    }
}

// ---------------- conv3: [32,64,9,9] * [64,64,3,3] s1 -> [32,64,7,7] relu ----------------
// grid 256 = (b, og of 8 oc). x (20.7KB) + w (18.4KB) in LDS.
// Threads tid<196: pos = tid/4, q = tid&3 -> 2 oc each.
__global__ __launch_bounds__(256) void conv3_k(const float* __restrict__ x,
                                               const float* __restrict__ w,
                                               const float* __restrict__ bias,
                                               float* __restrict__ y) {
    int b = blockIdx.x >> 3;
    int og = blockIdx.x & 7;
    int tid = threadIdx.x;
    __shared__ __align__(16) float xs[5184];    // [64ic][81]
    __shared__ __align__(16) float ws[8 * 576]; // [oc8][ic64][ky3][kx3]
    {
        const float4* xg = (const float4*)(x + (size_t)b * 5184);
        float4* xs4 = (float4*)xs;
        for (int i = tid; i < 1296; i += 256) xs4[i] = xg[i];
        const float4* wg = (const float4*)(w + og * 4608);
        float4* ws4 = (float4*)ws;
        for (int i = tid; i < 1152; i += 256) ws4[i] = wg[i];
    }
    __syncthreads();

    if (tid < 196) {
        int pos = tid >> 2, q = tid & 3;
        int oy = pos / 7, ox = pos % 7;
        float acc[2];
#pragma unroll
        for (int o = 0; o < 2; o++) acc[o] = bias[og * 8 + q * 2 + o];
        for (int ic = 0; ic < 64; ic++) {
            const float* xrow = xs + ic * 81 + oy * 9 + ox;
#pragma unroll
            for (int ky = 0; ky < 3; ky++) {
                float x0 = xrow[ky * 9], x1 = xrow[ky * 9 + 1], x2 = xrow[ky * 9 + 2];
                const float* wrow = ws + (q * 2) * 576 + ic * 9 + ky * 3;
#pragma unroll
                for (int o = 0; o < 2; o++) {
                    const float* wo = wrow + o * 576;
                    acc[o] += x0 * wo[0] + x1 * wo[1] + x2 * wo[2];
                }
            }
        }
#pragma unroll
        for (int o = 0; o < 2; o++)
            y[((size_t)(b * 64 + og * 8 + q * 2 + o)) * 49 + pos] = fmaxf(acc[o], 0.f);
    }
}

// ---------------- fc: [32,3136] @ [128,3136]^T + b -> h [32,128] ----------------
__global__ __launch_bounds__(256) void fc_k(const float* __restrict__ x,
                                            const float* __restrict__ w,
                                            const float* __restrict__ bias,
                                            float* __restrict__ h) {
    __shared__ float sx[3136];
    int b = blockIdx.x >> 3;
    int g = blockIdx.x & 7;
    int tid = threadIdx.x;
    const float4* xr = (const float4*)(x + (size_t)b * 3136);
    float4* sx4w = (float4*)sx;
    for (int i = tid; i < 784; i += 256) sx4w[i] = xr[i];
    __syncthreads();
    int oc_local = tid >> 4;
    int kslice = tid & 15;
    int oc = g * 16 + oc_local;
    const float4* wr = (const float4*)(w + (size_t)oc * 3136);
    const float4* sx4 = (const float4*)sx;
    float acc = 0.f;
#pragma unroll 7
    for (int j = 0; j < 49; j++) {
        int i = kslice + 16 * j;
        float4 a = sx4[i], c = wr[i];
        acc += a.x * c.x + a.y * c.y + a.z * c.z + a.w * c.w;
    }
#pragma unroll
    for (int m = 8; m >= 1; m >>= 1) acc += __shfl_xor(acc, m);
    if (kslice == 0) h[b * 128 + oc] = acc + bias[oc];
}

// ---------------- dist4: lane-per-row distances from a swizzled LDS key tile ----------------
__global__ __launch_bounds__(256) void dist4_k(const float* __restrict__ h,
                                               const int* __restrict__ actions,
                                               const float* __restrict__ keys,
                                               float* __restrict__ d2) {
    int a = blockIdx.y;
    int tid = threadIdx.x;
    int lane = tid & 63, wave = tid >> 6;
    __shared__ float4 tile[64 * 32];   // 32 KB, slot-rotated per row
    __shared__ float4 hl4[BB * 32];    // up to 16 KB used
    __shared__ int sl[BB];
    __shared__ int s_m;

    if (wave == 0) {
        int act = (lane < BB) ? actions[lane] : -1;
        ull mask = __ballot(act == a);
        if (act == a) {
            int pos = __popcll(mask & ((1ull << lane) - 1));
            sl[pos] = lane;
        }
        if (lane == 0) s_m = __popcll(mask);
    }
    __syncthreads();
    int m = s_m;
    if (m == 0) return;

    for (int i = tid; i < m * 32; i += 256) {
        int s = i >> 5, g = i & 31;
        hl4[i] = ((const float4*)(h + sl[s] * DD))[g];
    }

    int r0 = blockIdx.x * 64;
    int valid = min(64, NN - r0);
    const float4* kb4 = (const float4*)(keys + (size_t)a * NN * DD);
#pragma unroll
    for (int i = 0; i < 8; i++) {
        int idx = i * 256 + tid;
        int row = idx >> 5, g = idx & 31;
        if (row < valid)
            tile[row * 32 + ((g + (row & 31)) & 31)] = kb4[(size_t)(r0 + row) * 32 + g];
    }
    __syncthreads();

    int row = lane;
    if (row < valid) {
        int c = row & 31;
        const float4* trow = &tile[row * 32];
        for (int s = wave; s < m; s += 4) {
            const float4* hp = &hl4[s * 32];
            float acc = 0.f;
#pragma unroll 8
            for (int g = 0; g < 32; g++) {
                float4 kv = trow[(g + c) & 31];
                float4 hv = hp[g];
                float dx = hv.x - kv.x, dy = hv.y - kv.y;
                float dz = hv.z - kv.z, dw = hv.w - kv.w;
                acc += dx * dx + dy * dy + dz * dz + dw * dw;
            }
            d2[(size_t)sl[s] * NN + r0 + row] = acc;  // lane-coalesced
        }
    }
}

// ---------------- select: fused exact top-50 (two-level radix on float bits) + weighted sum ----
__global__ __launch_bounds__(1024) void select_k(const float* __restrict__ d2,
                                                 const float* __restrict__ values,
                                                 const int* __restrict__ actions,
                                                 float* __restrict__ q) {
    const int NB = 8160;
    const int CAP = 512;
    int b = blockIdx.x, tid = threadIdx.x;
    int lane = tid & 63, wave = tid >> 6;
    __shared__ int hist[NB];
    __shared__ int fhist[1024];
    __shared__ float cd[CAP];
    __shared__ int ci[CAP];
    __shared__ int scounter;
    __shared__ int s_t, s_below;
    __shared__ int s_ft;
    __shared__ int wsum[16];
    __shared__ float rw[16], rwv[16];

    const float* db = d2 + (size_t)b * NN;
    for (int i = tid; i < NB; i += 1024) hist[i] = 0;
    fhist[tid] = 0;
    if (tid == 0) scounter = 0;
    __syncthreads();

    for (int i = tid; i < NN; i += 1024)
        atomicAdd(&hist[__float_as_uint(db[i]) >> 18], 1);
    __syncthreads();

    {
        int s = 0;
#pragma unroll
        for (int u = 0; u < 8; u++) s += hist[tid * 8 + u];
        int sc = s;
#pragma unroll
        for (int m = 1; m < 64; m <<= 1) {
            int o = __shfl_up(sc, m);
            if (lane >= m) sc += o;
        }
        if (lane == 63) wsum[wave] = sc;
        __syncthreads();
        if (tid < 16) {
            int vc = wsum[tid];
            for (int m = 1; m < 16; m <<= 1) {
                int o = __shfl_up(vc, m);
                if (tid >= m) vc += o;
            }
            wsum[tid] = vc;
        }
        __syncthreads();
        int incl = ((wave == 0) ? 0 : wsum[wave - 1]) + sc;
        int excl = incl - s;
        if (excl < PP && incl >= PP) {
            int c = excl;
#pragma unroll
            for (int u = 0; u < 8; u++) {
                int bkt = tid * 8 + u;
                int hv = hist[bkt];
                if (c < PP && c + hv >= PP) { s_t = bkt; s_below = c; }
                c += hv;
            }
        }
    }
    __syncthreads();
    int t = s_t, below = s_below;

    for (int i = tid; i < NN; i += 1024) {
        unsigned bits = __float_as_uint(db[i]);
        if ((int)(bits >> 18) == t) atomicAdd(&fhist[(bits >> 8) & 1023], 1);
    }
    __syncthreads();

    {
        int s = fhist[tid];
        int sc = s;
#pragma unroll
        for (int m = 1; m < 64; m <<= 1) {
            int o = __shfl_up(sc, m);
            if (lane >= m) sc += o;
        }
        if (lane == 63) wsum[wave] = sc;
        __syncthreads();
        if (tid < 16) {
            int vc = wsum[tid];
            for (int m = 1; m < 16; m <<= 1) {
                int o = __shfl_up(vc, m);
                if (tid >= m) vc += o;
            }
            wsum[tid] = vc;
        }
        __syncthreads();
        int incl = ((wave == 0) ? 0 : wsum[wave - 1]) + sc;
        int excl = incl - s;
        if (below + excl < PP && below + incl >= PP) s_ft = tid;
    }
    __syncthreads();
    int ft = s_ft;

    for (int i = tid; i < NN; i += 1024) {
        unsigned bits = __float_as_uint(db[i]);
        int c = (int)(bits >> 18);
        bool take = (c < t) || (c == t && (int)((bits >> 8) & 1023) <= ft);
        if (take) {
            int slot = atomicAdd(&scounter, 1);
            if (slot < CAP) { cd[slot] = db[i]; ci[slot] = i; }
        }
    }
    __syncthreads();
    int k = min(scounter, CAP);

    float w = 0.f, wv = 0.f;
    int a = actions[b];
    for (int s = tid; s < k; s += 1024) {
        ull key = ((ull)__float_as_uint(cd[s]) << 32) | (unsigned)ci[s];
        int cnt = 0;
        for (int j = 0; j < k; j++) {
            ull kj = ((ull)__float_as_uint(cd[j]) << 32) | (unsigned)ci[j];
            cnt += (kj < key);
        }
        if (cnt < PP) {
            float dd = fmaxf(cd[s], 0.f);
            float ww = 1.f / (dd + DELTA);
            w += ww;
            wv += ww * values[(size_t)a * NN + ci[s]];
        }
    }
#pragma unroll
    for (int m = 32; m >= 1; m >>= 1) {
        w += __shfl_xor(w, m);
        wv += __shfl_xor(wv, m);
    }
    if (lane == 0) { rw[wave] = w; rwv[wave] = wv; }
    __syncthreads();
    if (tid < 16) {
        float tw = rw[tid], twv = rwv[tid];
#pragma unroll
        for (int m = 8; m >= 1; m >>= 1) {
            tw += __shfl_xor(tw, m);
            twv += __shfl_xor(twv, m);
        }
        if (tid == 0) q[b] = twv / tw;
    }
}

extern "C" void kernel_launch(void* const* d_in, const int* in_sizes, int n_in,
                              void* d_out, int out_size, void* d_ws, size_t ws_size,
                              hipStream_t stream) {
    const float* states = (const float*)d_in[0];
    const int* actions = (const int*)d_in[1];
    const float* c1w = (const float*)d_in[2];
    const float* c1b = (const float*)d_in[3];
    const float* c2w = (const float*)d_in[4];
    const float* c2b = (const float*)d_in[5];
    const float* c3w = (const float*)d_in[6];
    const float* c3b = (const float*)d_in[7];
    const float* fcw = (const float*)d_in[8];
    const float* fcb = (const float*)d_in[9];
    const float* keys = (const float*)d_in[10];
    const float* vals = (const float*)d_in[11];
    float* out = (float*)d_out;

    float* ws = (float*)d_ws;
    float* c1o = ws;                    // 409600
    float* c2o = c1o + 409600;          // 165888
    float* c3o = c2o + 165888;          // 100352
    float* h   = c3o + 100352;          // 4096
    float* d2  = h + 4096;              // 640000

    conv1_k<<<128, 256, 0, stream>>>(states, c1w, c1b, c1o);
    conv2_k<<<256, 256, 0, stream>>>(c1o, c2w, c2b, c2o);
    conv3_k<<<256, 256, 0, stream>>>(c2o, c3w, c3b, c3o);
    fc_k<<<256, 256, 0, stream>>>(c3o, fcw, fcb, h);
    dist4_k<<<dim3(313, AA), 256, 0, stream>>>(h, actions, keys, d2);
    select_k<<<BB, 1024, 0, stream>>>(d2, vals, actions, out);
}